// Round 1
// baseline (1018.888 us; speedup 1.0000x reference)
//
#include <hip/hip_runtime.h>
#include <hip/hip_bf16.h>

typedef __bf16 bf16x8 __attribute__((ext_vector_type(8)));
typedef float  f32x4  __attribute__((ext_vector_type(4)));

namespace {
constexpr int NHEADS = 8;
constexpr int BLKSZ  = 8;
constexpr int HALO_  = 2;
constexpr int WINSZ  = 12;
constexpr int NBW    = 24;   // blocks per row/col
constexpr int NBLK   = 576;  // 24*24
constexpr int IMG    = 192;  // H == W
constexpr int CIN    = 256;
constexpr int SWIN   = 144;  // 12*12 window positions
constexpr int NQ     = 64;   // 8*8 interior positions

// LDS layout (bf16 elements; rows padded +8 to dodge 32-bank stride)
constexpr int XW_LDW = 72;                              // [144][64+8]
constexpr int WT_LDW = 72;                              // [256][64+8]
constexpr int PJ_LDW = 264;                             // [144][256+8]
constexpr int XW_OFF = 0;
constexpr int WT_OFF = XW_OFF + SWIN * XW_LDW * 2;      // 20736
constexpr int PJ_OFF = WT_OFF + 256  * WT_LDW * 2;      // 57600
constexpr int LDS_BYTES = PJ_OFF + SWIN * PJ_LDW * 2;   // 133632
}

__device__ __forceinline__ unsigned pack2bf(float a, float b) {
    union { __bf16 h[2]; unsigned u; } p;
    p.h[0] = (__bf16)a; p.h[1] = (__bf16)b;
    return p.u;
}

__global__ __launch_bounds__(512, 2)
void fused_winattn_qk(const float* __restrict__ x,
                      const float* __restrict__ qw,
                      const float* __restrict__ kvw,
                      float* __restrict__ out) {
    extern __shared__ char lds[];
    __bf16* XW = (__bf16*)(lds + XW_OFF);
    __bf16* WT = (__bf16*)(lds + WT_OFF);
    __bf16* PJ = (__bf16*)(lds + PJ_OFF);

    const int tid  = threadIdx.x;
    const int wave = tid >> 6;
    const int lane = tid & 63;
    const int l16  = lane & 15;
    const int lg   = lane >> 4;     // 0..3 (k-group)

    const int nb = blockIdx.x;      // 0..575
    const int b  = blockIdx.y;      // 0..3
    const int hb = nb / NBW, wb = nb - hb * NBW;
    const int h0 = hb * BLKSZ - HALO_, w0 = wb * BLKSZ - HALO_;

    // projection accumulators: wave owns o-tiles {2*wave, 2*wave+1} x 9 s-tiles
    const f32x4 vzero = {0.f, 0.f, 0.f, 0.f};
    f32x4 acc[2][9];
    #pragma unroll
    for (int i = 0; i < 2; ++i)
        #pragma unroll
        for (int j = 0; j < 9; ++j)
            acc[i][j] = vzero;

    for (int ch = 0; ch < 4; ++ch) {
        const int c0 = ch * 64;
        // ---- stage x window chunk: 32 channel-pairs x 144 positions ----
        {
            const float* xb = x + ((size_t)b * CIN + c0) * (IMG * IMG);
            #pragma unroll
            for (int e = 0; e < 9; ++e) {
                int flat = e * 512 + tid;            // 0..4607
                int s  = flat % SWIN;
                int cc = (flat / SWIN) * 2;          // even channel within chunk
                int ii = s / WINSZ, jj = s - ii * WINSZ;
                int hh = h0 + ii, ww = w0 + jj;
                float v0 = 0.f, v1 = 0.f;
                if ((unsigned)hh < (unsigned)IMG && (unsigned)ww < (unsigned)IMG) {
                    size_t off = (size_t)cc * (IMG * IMG) + (size_t)hh * IMG + ww;
                    v0 = xb[off];
                    v1 = xb[off + (size_t)(IMG * IMG)];
                }
                *(unsigned*)&XW[s * XW_LDW + cc] = pack2bf(v0, v1);
            }
        }
        // ---- stage weights chunk: 256 o-rows x 32 channel-pairs ----
        {
            #pragma unroll
            for (int e = 0; e < 16; ++e) {
                int flat = e * 512 + tid;            // 0..8191
                int cc = (flat & 31) * 2;
                int o  = flat >> 5;                  // 0..255
                const float* wrow;
                if (o < 128) {
                    wrow = qw + (size_t)o * CIN;     // q channels: o = h*16+d
                } else {
                    int oo = o - 128;                // k channels: kv row h*48+d, d<16
                    wrow = kvw + (size_t)((oo >> 4) * 48 + (oo & 15)) * CIN;
                }
                float2 v = *(const float2*)(wrow + c0 + cc);
                *(unsigned*)&WT[o * WT_LDW + cc] = pack2bf(v.x, v.y);
            }
        }
        __syncthreads();
        // ---- MFMA: proj[o][s] += W[o][c] * Xwin[c][s] over this 64-ch chunk ----
        #pragma unroll
        for (int ks = 0; ks < 2; ++ks) {
            const int kk = ks * 32;
            bf16x8 afr0 = *(const bf16x8*)&WT[(wave * 32 + l16)      * WT_LDW + kk + lg * 8];
            bf16x8 afr1 = *(const bf16x8*)&WT[(wave * 32 + 16 + l16) * WT_LDW + kk + lg * 8];
            #pragma unroll
            for (int st = 0; st < 9; ++st) {
                bf16x8 bfr = *(const bf16x8*)&XW[(st * 16 + l16) * XW_LDW + kk + lg * 8];
                acc[0][st] = __builtin_amdgcn_mfma_f32_16x16x32_bf16(afr0, bfr, acc[0][st], 0, 0, 0);
                acc[1][st] = __builtin_amdgcn_mfma_f32_16x16x32_bf16(afr1, bfr, acc[1][st], 0, 0, 0);
            }
        }
        __syncthreads();
    }

    // ---- spill projections to LDS as bf16, layout PJ[s][o] ----
    // D-frag: o_local = lg*4 + r, s_local = l16 -> 4 consecutive o at one s = b64 write
    #pragma unroll
    for (int ot = 0; ot < 2; ++ot) {
        const int o = wave * 32 + ot * 16 + lg * 4;
        #pragma unroll
        for (int st = 0; st < 9; ++st) {
            const int s = st * 16 + l16;
            union { __bf16 h[4]; unsigned u[2]; } p;
            #pragma unroll
            for (int r = 0; r < 4; ++r) p.h[r] = (__bf16)acc[ot][st][r];
            *(uint2*)&PJ[s * PJ_LDW + o] = make_uint2(p.u[0], p.u[1]);
        }
    }
    __syncthreads();

    // ---- QK^T, one head per wave; K=32 MFMA with upper 16 k zeroed (d=16) ----
    const int head = wave;
    bf16x8 zf;
    #pragma unroll
    for (int i = 0; i < 8; ++i) zf[i] = (__bf16)0.f;

    // B-frags from q-proj (interior 8x8 positions remapped into the 12x12 window)
    bf16x8 bq[4];
    #pragma unroll
    for (int qt = 0; qt < 4; ++qt) {
        bq[qt] = zf;
        if (lg < 2) {
            int qsg  = qt * 16 + l16;                       // 0..63
            int srow = ((qsg >> 3) + HALO_) * WINSZ + (qsg & 7) + HALO_;
            bq[qt] = *(const bf16x8*)&PJ[srow * PJ_LDW + head * 16 + lg * 8];
        }
    }

    float* outb = out + ((size_t)(b * NHEADS + head) * NBLK + nb) * (NQ * SWIN);
    #pragma unroll
    for (int kt = 0; kt < 9; ++kt) {
        bf16x8 ak = zf;
        if (lg < 2) {
            ak = *(const bf16x8*)&PJ[(kt * 16 + l16) * PJ_LDW + 128 + head * 16 + lg * 8];
        }
        #pragma unroll
        for (int qt = 0; qt < 4; ++qt) {
            // OUT^T tile: M = ks, N = qs -> lane regs are 4 consecutive ks
            f32x4 d = __builtin_amdgcn_mfma_f32_16x16x32_bf16(ak, bq[qt], vzero, 0, 0, 0);
            int qs  = qt * 16 + l16;
            int ksb = kt * 16 + lg * 4;
            *(f32x4*)&outb[(size_t)qs * SWIN + ksb] = d;
        }
    }
}

extern "C" void kernel_launch(void* const* d_in, const int* in_sizes, int n_in,
                              void* d_out, int out_size, void* d_ws, size_t ws_size,
                              hipStream_t stream) {
    const float* x   = (const float*)d_in[0];
    const float* qw  = (const float*)d_in[1];
    const float* kvw = (const float*)d_in[2];
    float* out = (float*)d_out;
    dim3 grid(NBLK, 4, 1);
    dim3 block(512, 1, 1);
    fused_winattn_qk<<<grid, block, LDS_BYTES, stream>>>(x, qw, kvw, out);
}